// Round 10
// baseline (123.589 us; speedup 1.0000x reference)
//
#include <hip/hip_runtime.h>

// NCF fused forward, v10: wave-local fp8 tower, zero block barriers,
// wave-local LDS fences (lgkmcnt(0) + memory clobber + sched_barrier) between phases.

typedef __attribute__((ext_vector_type(8))) short bf16x8;
typedef __attribute__((ext_vector_type(4))) float f32x4;

union i2l { int2 i; long v; };

__device__ __forceinline__ short f2bf(float x){
  unsigned u = __float_as_uint(x);
  u += 0x7fffu + ((u >> 16) & 1u);
  return (short)(u >> 16);
}
__device__ __forceinline__ unsigned char f2fp8(float x){
  return (unsigned char)(__builtin_amdgcn_cvt_pk_fp8_f32(x, 0.f, 0, false) & 0xFF);
}
__device__ __forceinline__ void wave_lds_fence(){
  asm volatile("s_waitcnt lgkmcnt(0)" ::: "memory");
  __builtin_amdgcn_sched_barrier(0);
}

// ws layout (bytes):
//   0      W1uT bf16 [128][64]  (16384)
//   16384  W1iT fp8  [128][64]  (8192)
//   24576  W2T  fp8  [64][128]  (8192)
//   32768  W3T  fp8  [32][64]   (2048)
//   34816  c1   f32  [128]
//   36864  Xu   f32  [B][128];  then wup f32 [B][64];  cu f32 [B]

__global__ __launch_bounds__(256) void ncf_prep_w(
    const float* __restrict__ W1, const float* __restrict__ W2,
    const float* __restrict__ W3, const float* __restrict__ b1,
    const float* __restrict__ bi_mlp, char* __restrict__ ws)
{
  if (blockIdx.x == 104){
    int j = threadIdx.x;
    if (j < 128){
      float acc = b1[j];
      #pragma unroll 4
      for (int k = 0; k < 64; k++)
        acc += bi_mlp[k] * W1[(64 + k)*128 + j];
      ((float*)(ws + 34816))[j] = acc;
    }
    return;
  }
  int i = blockIdx.x * 256 + threadIdx.x;
  if (i < 8192){                                 // W1uT bf16 [col][k] = W1[k][col]
    int col = i >> 6, k = i & 63;
    ((short*)ws)[i] = f2bf(W1[k*128 + col]);
  } else if (i < 16384){                         // W1iT fp8 [col][k] = W1[64+k][col]
    int t = i - 8192; int col = t >> 6, k = t & 63;
    ((unsigned char*)(ws + 16384))[t] = f2fp8(W1[(64 + k)*128 + col]);
  } else if (i < 24576){                         // W2T fp8 [col][k] = W2[k][col]
    int t = i - 16384; int col = t >> 7, k = t & 127;
    ((unsigned char*)(ws + 24576))[t] = f2fp8(W2[k*64 + col]);
  } else {                                       // W3T fp8 [col][k] = W3[k][col]
    int t = i - 24576; int col = t >> 6, k = t & 63;
    ((unsigned char*)(ws + 32768))[t] = f2fp8(W3[k*32 + col]);
  }
}

// ---- prep_u: 64 users per block, bf16 MFMA GEMM K=64 ----
__global__ __launch_bounds__(256) void ncf_prep_u(
    const int* __restrict__ user,
    const float* __restrict__ Wu_gmf, const float* __restrict__ bu_gmf,
    const float* __restrict__ Wu_mlp, const float* __restrict__ bu_mlp,
    const float* __restrict__ bi_gmf, const float* __restrict__ Wp,
    const short* __restrict__ W1uT, const float* __restrict__ c1,
    float* __restrict__ Xu, float* __restrict__ wup, float* __restrict__ cu)
{
  __shared__ __align__(16) short s_eu[64][72];
  const int tid = threadIdx.x;
  const int r = tid >> 2, q = tid & 3;
  const int b = blockIdx.x * 64 + r;
  long u = (long)user[b];
  {
    const float4* ump = (const float4*)(Wu_mlp + u*64) + q*4;
    const float4* bmp = (const float4*)(bu_mlp) + q*4;
    const float4* ugp = (const float4*)(Wu_gmf + u*64) + q*4;
    const float4* bgp = (const float4*)(bu_gmf) + q*4;
    const float4* wpp = (const float4*)(Wp) + q*4;
    const float4* bip = (const float4*)(bi_gmf) + q*4;
    float4* wdst = (float4*)(wup + (long)b*64) + q*4;
    bf16x8 ea[2];
    float cacc = 0.f;
    #pragma unroll
    for (int j = 0; j < 4; j++){
      float4 m = ump[j], mb = bmp[j];
      int h = j >> 1, s = (j & 1) * 4;
      ea[h][s+0] = f2bf(m.x + mb.x); ea[h][s+1] = f2bf(m.y + mb.y);
      ea[h][s+2] = f2bf(m.z + mb.z); ea[h][s+3] = f2bf(m.w + mb.w);
      float4 g = ugp[j], gb = bgp[j], wp = wpp[j], bi = bip[j];
      float4 wg; wg.x = (g.x+gb.x)*wp.x; wg.y = (g.y+gb.y)*wp.y;
                 wg.z = (g.z+gb.z)*wp.z; wg.w = (g.w+gb.w)*wp.w;
      wdst[j] = wg;
      cacc += wg.x*bi.x + wg.y*bi.y + wg.z*bi.z + wg.w*bi.w;
    }
    *(bf16x8*)&s_eu[r][q*16]     = ea[0];
    *(bf16x8*)&s_eu[r][q*16 + 8] = ea[1];
    cacc += __shfl_xor(cacc, 1);
    cacc += __shfl_xor(cacc, 2);
    if (q == 0) cu[b] = cacc;
  }
  __syncthreads();

  const int w = tid >> 6, l = tid & 63, lr = l & 15, lg = l >> 4;
  f32x4 acc[4][2];
  #pragma unroll
  for (int mt = 0; mt < 4; mt++)
    #pragma unroll
    for (int nt = 0; nt < 2; nt++)
      acc[mt][nt] = (f32x4){0.f, 0.f, 0.f, 0.f};
  #pragma unroll
  for (int ks = 0; ks < 2; ks++){
    bf16x8 af[4];
    #pragma unroll
    for (int mt = 0; mt < 4; mt++)
      af[mt] = *(const bf16x8*)&s_eu[mt*16 + lr][ks*32 + lg*8];
    #pragma unroll
    for (int nt = 0; nt < 2; nt++){
      bf16x8 bf_ = *(const bf16x8*)&W1uT[(w*32 + nt*16 + lr)*64 + ks*32 + lg*8];
      #pragma unroll
      for (int mt = 0; mt < 4; mt++)
        acc[mt][nt] = __builtin_amdgcn_mfma_f32_16x16x32_bf16(af[mt], bf_, acc[mt][nt], 0, 0, 0);
    }
  }
  #pragma unroll
  for (int nt = 0; nt < 2; nt++){
    int col = w*32 + nt*16 + lr;
    float cc = c1[col];
    #pragma unroll
    for (int mt = 0; mt < 4; mt++)
      #pragma unroll
      for (int rr = 0; rr < 4; rr++){
        int row = mt*16 + lg*4 + rr;
        Xu[(long)(blockIdx.x*64 + row)*128 + col] = acc[mt][nt][rr] + cc;
      }
  }
}

// ---- main: one 16-pair tile per wave, no block barriers ----
__global__ __launch_bounds__(256) void ncf_main(
    const int* __restrict__ item,
    const float* __restrict__ Wi_mlp, const float* __restrict__ Wi_gmf,
    const unsigned char* __restrict__ W1iT, const unsigned char* __restrict__ W2T,
    const unsigned char* __restrict__ W3T,
    const float* __restrict__ b2, const float* __restrict__ b3,
    const float* __restrict__ Wp, const float* __restrict__ bp,
    const float* __restrict__ Xu, const float* __restrict__ wup,
    const float* __restrict__ cu,
    float* __restrict__ out, int N, int total, int nmt, int Bsz)
{
  __shared__ __align__(16) unsigned char s_h1[4][16*136];  // per-wave h1 fp8
  __shared__ __align__(16) unsigned char s_h2[4][16*72];   // per-wave h2 fp8
  __shared__ __align__(16) float s_xu[4][256];             // per-wave 2 Xu rows

  const int tid = threadIdx.x;
  const int w  = tid >> 6, l = tid & 63;
  const int lr = l & 15,  lg = l >> 4;
  unsigned char* h1 = &s_h1[w][0];
  unsigned char* h2 = &s_h2[w][0];
  float* xu = &s_xu[w][0];

  const int mt0 = blockIdx.x*4 + w;
  if (mt0 >= nmt) return;                 // whole wave exits; no barriers -> safe
  const int p0  = mt0 * 16;
  const int b0  = p0 / N;
  const int thr = (b0 + 1) * N;

  int p = p0 + lr; if (p >= total) p = total - 1;
  const int  bA = b0 + ((p >= thr) ? 1 : 0);
  const long ib = (long)item[p] * 64;

  // ---- item mlp row -> fp8 B-fragments (registers) ----
  long a1[2];
  #pragma unroll
  for (int ks = 0; ks < 2; ks++){
    const float4* ap = (const float4*)(Wi_mlp + ib + ks*32 + lg*8);
    float4 x = ap[0], y = ap[1];
    int t0 = __builtin_amdgcn_cvt_pk_fp8_f32(x.x, x.y, 0, false);
    t0     = __builtin_amdgcn_cvt_pk_fp8_f32(x.z, x.w, t0, true);
    int t1 = __builtin_amdgcn_cvt_pk_fp8_f32(y.x, y.y, 0, false);
    t1     = __builtin_amdgcn_cvt_pk_fp8_f32(y.z, y.w, t1, true);
    i2l u; u.i.x = t0; u.i.y = t1;
    a1[ks] = u.v;
  }

  // ---- gmf partial dot (16 elems/lane, reduce over lg) ----
  float pg;
  {
    const float4* gp = (const float4*)(Wi_gmf + ib + lg*16);
    const float4* wq = (const float4*)(wup + (long)bA*64 + lg*16);
    float s = 0.f;
    #pragma unroll
    for (int j = 0; j < 4; j++){
      float4 g = gp[j], v = wq[j];
      s += g.x*v.x + g.y*v.y + g.z*v.z + g.w*v.w;
    }
    s += __shfl_xor(s, 16);
    s += __shfl_xor(s, 32);
    pg = s + cu[bA];
  }

  // ---- stage the <=2 Xu rows into wave-private LDS ----
  {
    int row = l >> 5;                  // 0 or 1
    int col = (l & 31) * 4;
    int bb = b0 + row; if (bb >= Bsz) bb = Bsz - 1;
    *(float4*)&xu[row*128 + col] = *(const float4*)&Xu[(long)bb*128 + col];
  }
  wave_lds_fence();                    // xu writes visible to whole wave
  const int bl = (p0 + lr >= thr) ? 1 : 0;   // my pair's Xu row

  // ---- G1: D[col128][pair16] fp8, K=64; +Xu, relu -> h1 (fp8) ----
  {
    f32x4 acc[8];
    #pragma unroll
    for (int mt = 0; mt < 8; mt++) acc[mt] = (f32x4){0.f,0.f,0.f,0.f};
    #pragma unroll
    for (int ks = 0; ks < 2; ks++)
      #pragma unroll
      for (int mt = 0; mt < 8; mt++){
        long af = *(const long*)&W1iT[(mt*16 + lr)*64 + ks*32 + lg*8];
        acc[mt] = __builtin_amdgcn_mfma_f32_16x16x32_fp8_fp8(af, a1[ks], acc[mt], 0, 0, 0);
      }
    #pragma unroll
    for (int mt = 0; mt < 8; mt++){
      int colb = mt*16 + lg*4;
      float4 xv = *(const float4*)&xu[bl*128 + colb];
      float v0 = acc[mt][0] + xv.x; v0 = v0 > 0.f ? v0 : 0.f;
      float v1 = acc[mt][1] + xv.y; v1 = v1 > 0.f ? v1 : 0.f;
      float v2 = acc[mt][2] + xv.z; v2 = v2 > 0.f ? v2 : 0.f;
      float v3 = acc[mt][3] + xv.w; v3 = v3 > 0.f ? v3 : 0.f;
      int t_ = __builtin_amdgcn_cvt_pk_fp8_f32(v0, v1, 0, false);
      t_     = __builtin_amdgcn_cvt_pk_fp8_f32(v2, v3, t_, true);
      *(int*)&h1[lr*136 + colb] = t_;
    }
  }
  wave_lds_fence();                    // h1 writes complete before G2 reads

  // ---- G2: D[col64][pair16] fp8, K=128; +b2, relu -> h2 (fp8) ----
  {
    f32x4 acc[4];
    #pragma unroll
    for (int mt = 0; mt < 4; mt++) acc[mt] = (f32x4){0.f,0.f,0.f,0.f};
    #pragma unroll
    for (int ks = 0; ks < 4; ks++){
      long bf_ = *(const long*)&h1[lr*136 + ks*32 + lg*8];
      #pragma unroll
      for (int mt = 0; mt < 4; mt++){
        long af = *(const long*)&W2T[(mt*16 + lr)*128 + ks*32 + lg*8];
        acc[mt] = __builtin_amdgcn_mfma_f32_16x16x32_fp8_fp8(af, bf_, acc[mt], 0, 0, 0);
      }
    }
    #pragma unroll
    for (int mt = 0; mt < 4; mt++){
      int colb = mt*16 + lg*4;
      float4 b2v = *(const float4*)&b2[colb];
      float v0 = acc[mt][0] + b2v.x; v0 = v0 > 0.f ? v0 : 0.f;
      float v1 = acc[mt][1] + b2v.y; v1 = v1 > 0.f ? v1 : 0.f;
      float v2 = acc[mt][2] + b2v.z; v2 = v2 > 0.f ? v2 : 0.f;
      float v3 = acc[mt][3] + b2v.w; v3 = v3 > 0.f ? v3 : 0.f;
      int t_ = __builtin_amdgcn_cvt_pk_fp8_f32(v0, v1, 0, false);
      t_     = __builtin_amdgcn_cvt_pk_fp8_f32(v2, v3, t_, true);
      *(int*)&h2[lr*72 + colb] = t_;
    }
  }
  wave_lds_fence();                    // h2 writes complete before G3 reads

  // ---- G3: D[col32][pair16] fp8, K=64; final dot + sigmoid ----
  {
    f32x4 acc[2];
    #pragma unroll
    for (int mt = 0; mt < 2; mt++) acc[mt] = (f32x4){0.f,0.f,0.f,0.f};
    #pragma unroll
    for (int ks = 0; ks < 2; ks++){
      long bf_ = *(const long*)&h2[lr*72 + ks*32 + lg*8];
      #pragma unroll
      for (int mt = 0; mt < 2; mt++){
        long af = *(const long*)&W3T[(mt*16 + lr)*64 + ks*32 + lg*8];
        acc[mt] = __builtin_amdgcn_mfma_f32_16x16x32_fp8_fp8(af, bf_, acc[mt], 0, 0, 0);
      }
    }
    float t = 0.f;
    #pragma unroll
    for (int mt = 0; mt < 2; mt++){
      int colb = mt*16 + lg*4;
      float4 b3v = *(const float4*)&b3[colb];
      float4 wpv = *(const float4*)&Wp[64 + colb];
      float v0 = acc[mt][0] + b3v.x; v0 = v0 > 0.f ? v0 : 0.f;
      float v1 = acc[mt][1] + b3v.y; v1 = v1 > 0.f ? v1 : 0.f;
      float v2 = acc[mt][2] + b3v.z; v2 = v2 > 0.f ? v2 : 0.f;
      float v3 = acc[mt][3] + b3v.w; v3 = v3 > 0.f ? v3 : 0.f;
      t += v0*wpv.x + v1*wpv.y + v2*wpv.z + v3*wpv.w;
    }
    t += __shfl_xor(t, 16);
    t += __shfl_xor(t, 32);
    if (l < 16 && p0 + lr < total){
      float z = t + pg + bp[0];
      out[p0 + lr] = 1.f / (1.f + __expf(-z));
    }
  }
}

extern "C" void kernel_launch(void* const* d_in, const int* in_sizes, int n_in,
                              void* d_out, int out_size, void* d_ws, size_t ws_size,
                              hipStream_t stream)
{
  const int*   user   = (const int*)  d_in[0];
  const int*   item   = (const int*)  d_in[1];
  const float* Wu_gmf = (const float*)d_in[3];
  const float* bu_gmf = (const float*)d_in[4];
  const float* Wu_mlp = (const float*)d_in[5];
  const float* bu_mlp = (const float*)d_in[6];
  const float* Wi_gmf = (const float*)d_in[7];
  const float* bi_gmf = (const float*)d_in[8];
  const float* Wi_mlp = (const float*)d_in[9];
  const float* bi_mlp = (const float*)d_in[10];
  const float* W1     = (const float*)d_in[11];
  const float* b1     = (const float*)d_in[12];
  const float* W2     = (const float*)d_in[13];
  const float* b2     = (const float*)d_in[14];
  const float* W3     = (const float*)d_in[15];
  const float* b3     = (const float*)d_in[16];
  const float* Wp     = (const float*)d_in[17];
  const float* bp     = (const float*)d_in[18];

  int B     = in_sizes[0];            // 4096
  int total = in_sizes[1];            // 409600
  int N     = total / B;              // 100

  char* wsb = (char*)d_ws;
  short*         W1uT = (short*)wsb;
  unsigned char* W1iT = (unsigned char*)(wsb + 16384);
  unsigned char* W2T  = (unsigned char*)(wsb + 24576);
  unsigned char* W3T  = (unsigned char*)(wsb + 32768);
  float*         c1   = (float*)(wsb + 34816);
  float*         Xu   = (float*)(wsb + 36864);
  float*         wup  = Xu  + (size_t)B * 128;
  float*         cuv  = wup + (size_t)B * 64;

  ncf_prep_w<<<105, 256, 0, stream>>>(W1, W2, W3, b1, bi_mlp, wsb);
  ncf_prep_u<<<B/64, 256, 0, stream>>>(user, Wu_gmf, bu_gmf, Wu_mlp, bu_mlp,
                                       bi_gmf, Wp, W1uT, c1, Xu, wup, cuv);

  int nmt  = (total + 15) / 16;       // 25600 tiles
  int nblk = (nmt + 3) / 4;           // 6400 blocks, 1 tile per wave
  ncf_main<<<nblk, 256, 0, stream>>>(item, Wi_mlp, Wi_gmf,
      W1iT, W2T, W3T, b2, b3, Wp, bp, Xu, wup, cuv,
      (float*)d_out, N, total, nmt, B);
}

// Round 11
// 91.937 us; speedup vs baseline: 1.3443x; 1.3443x over previous
//
#include <hip/hip_runtime.h>

// NCF fused forward, v11: v8 block structure (64 pairs, fp8 tower, swapped GEMMs)
// with wave-local G1 (item frags in registers), per-wave Xu staging, 2 barriers.

typedef __attribute__((ext_vector_type(8))) short bf16x8;
typedef __attribute__((ext_vector_type(4))) float f32x4;

union i2l { int2 i; long v; };

__device__ __forceinline__ short f2bf(float x){
  unsigned u = __float_as_uint(x);
  u += 0x7fffu + ((u >> 16) & 1u);
  return (short)(u >> 16);
}
__device__ __forceinline__ unsigned char f2fp8(float x){
  return (unsigned char)(__builtin_amdgcn_cvt_pk_fp8_f32(x, 0.f, 0, false) & 0xFF);
}
__device__ __forceinline__ void wave_lds_fence(){
  asm volatile("s_waitcnt lgkmcnt(0)" ::: "memory");
  __builtin_amdgcn_sched_barrier(0);
}

// ws layout (bytes):
//   0      W1uT bf16 [128][64]  (16384)
//   16384  W1iT fp8  [128][64]  (8192)
//   24576  W2T  fp8  [64][128]  (8192)
//   32768  W3T  fp8  [32][64]   (2048)
//   34816  c1   f32  [128]
//   36864  Xu   f32  [B][128];  then wup f32 [B][64];  cu f32 [B]

__global__ __launch_bounds__(256) void ncf_prep_w(
    const float* __restrict__ W1, const float* __restrict__ W2,
    const float* __restrict__ W3, const float* __restrict__ b1,
    const float* __restrict__ bi_mlp, char* __restrict__ ws)
{
  if (blockIdx.x == 104){
    int j = threadIdx.x;
    if (j < 128){
      float acc = b1[j];
      #pragma unroll 4
      for (int k = 0; k < 64; k++)
        acc += bi_mlp[k] * W1[(64 + k)*128 + j];
      ((float*)(ws + 34816))[j] = acc;
    }
    return;
  }
  int i = blockIdx.x * 256 + threadIdx.x;
  if (i < 8192){                                 // W1uT bf16 [col][k] = W1[k][col]
    int col = i >> 6, k = i & 63;
    ((short*)ws)[i] = f2bf(W1[k*128 + col]);
  } else if (i < 16384){                         // W1iT fp8 [col][k] = W1[64+k][col]
    int t = i - 8192; int col = t >> 6, k = t & 63;
    ((unsigned char*)(ws + 16384))[t] = f2fp8(W1[(64 + k)*128 + col]);
  } else if (i < 24576){                         // W2T fp8 [col][k] = W2[k][col]
    int t = i - 16384; int col = t >> 7, k = t & 127;
    ((unsigned char*)(ws + 24576))[t] = f2fp8(W2[k*64 + col]);
  } else {                                       // W3T fp8 [col][k] = W3[k][col]
    int t = i - 24576; int col = t >> 6, k = t & 63;
    ((unsigned char*)(ws + 32768))[t] = f2fp8(W3[k*32 + col]);
  }
}

// ---- prep_u: 64 users per block, bf16 MFMA GEMM K=64 ----
__global__ __launch_bounds__(256) void ncf_prep_u(
    const int* __restrict__ user,
    const float* __restrict__ Wu_gmf, const float* __restrict__ bu_gmf,
    const float* __restrict__ Wu_mlp, const float* __restrict__ bu_mlp,
    const float* __restrict__ bi_gmf, const float* __restrict__ Wp,
    const short* __restrict__ W1uT, const float* __restrict__ c1,
    float* __restrict__ Xu, float* __restrict__ wup, float* __restrict__ cu)
{
  __shared__ __align__(16) short s_eu[64][72];
  const int tid = threadIdx.x;
  const int r = tid >> 2, q = tid & 3;
  const int b = blockIdx.x * 64 + r;
  long u = (long)user[b];
  {
    const float4* ump = (const float4*)(Wu_mlp + u*64) + q*4;
    const float4* bmp = (const float4*)(bu_mlp) + q*4;
    const float4* ugp = (const float4*)(Wu_gmf + u*64) + q*4;
    const float4* bgp = (const float4*)(bu_gmf) + q*4;
    const float4* wpp = (const float4*)(Wp) + q*4;
    const float4* bip = (const float4*)(bi_gmf) + q*4;
    float4* wdst = (float4*)(wup + (long)b*64) + q*4;
    bf16x8 ea[2];
    float cacc = 0.f;
    #pragma unroll
    for (int j = 0; j < 4; j++){
      float4 m = ump[j], mb = bmp[j];
      int h = j >> 1, s = (j & 1) * 4;
      ea[h][s+0] = f2bf(m.x + mb.x); ea[h][s+1] = f2bf(m.y + mb.y);
      ea[h][s+2] = f2bf(m.z + mb.z); ea[h][s+3] = f2bf(m.w + mb.w);
      float4 g = ugp[j], gb = bgp[j], wp = wpp[j], bi = bip[j];
      float4 wg; wg.x = (g.x+gb.x)*wp.x; wg.y = (g.y+gb.y)*wp.y;
                 wg.z = (g.z+gb.z)*wp.z; wg.w = (g.w+gb.w)*wp.w;
      wdst[j] = wg;
      cacc += wg.x*bi.x + wg.y*bi.y + wg.z*bi.z + wg.w*bi.w;
    }
    *(bf16x8*)&s_eu[r][q*16]     = ea[0];
    *(bf16x8*)&s_eu[r][q*16 + 8] = ea[1];
    cacc += __shfl_xor(cacc, 1);
    cacc += __shfl_xor(cacc, 2);
    if (q == 0) cu[b] = cacc;
  }
  __syncthreads();

  const int w = tid >> 6, l = tid & 63, lr = l & 15, lg = l >> 4;
  f32x4 acc[4][2];
  #pragma unroll
  for (int mt = 0; mt < 4; mt++)
    #pragma unroll
    for (int nt = 0; nt < 2; nt++)
      acc[mt][nt] = (f32x4){0.f, 0.f, 0.f, 0.f};
  #pragma unroll
  for (int ks = 0; ks < 2; ks++){
    bf16x8 af[4];
    #pragma unroll
    for (int mt = 0; mt < 4; mt++)
      af[mt] = *(const bf16x8*)&s_eu[mt*16 + lr][ks*32 + lg*8];
    #pragma unroll
    for (int nt = 0; nt < 2; nt++){
      bf16x8 bf_ = *(const bf16x8*)&W1uT[(w*32 + nt*16 + lr)*64 + ks*32 + lg*8];
      #pragma unroll
      for (int mt = 0; mt < 4; mt++)
        acc[mt][nt] = __builtin_amdgcn_mfma_f32_16x16x32_bf16(af[mt], bf_, acc[mt][nt], 0, 0, 0);
    }
  }
  #pragma unroll
  for (int nt = 0; nt < 2; nt++){
    int col = w*32 + nt*16 + lr;
    float cc = c1[col];
    #pragma unroll
    for (int mt = 0; mt < 4; mt++)
      #pragma unroll
      for (int rr = 0; rr < 4; rr++){
        int row = mt*16 + lg*4 + rr;
        Xu[(long)(blockIdx.x*64 + row)*128 + col] = acc[mt][nt][rr] + cc;
      }
  }
}

// ---- main: 64 pairs/block, wave-local G1, 2 barriers ----
__global__ __launch_bounds__(256) void ncf_main(
    const int* __restrict__ item,
    const float* __restrict__ Wi_mlp, const float* __restrict__ Wi_gmf,
    const unsigned char* __restrict__ W1iT, const unsigned char* __restrict__ W2T,
    const unsigned char* __restrict__ W3T,
    const float* __restrict__ b2, const float* __restrict__ b3,
    const float* __restrict__ Wp, const float* __restrict__ bp,
    const float* __restrict__ Xu, const float* __restrict__ wup,
    const float* __restrict__ cu,
    float* __restrict__ out, int N, int total, int Bsz)
{
  __shared__ __align__(16) unsigned char s_h1[64][144];   // h1 fp8 [pair][col]
  __shared__ __align__(16) unsigned char s_h2[64][72];    // h2 fp8 [pair][col]
  __shared__ __align__(16) float s_xu[4][2][128];         // per-wave Xu rows

  const int tid = threadIdx.x;
  const int w   = tid >> 6, l = tid & 63;
  const int lr  = l & 15,  lg = l >> 4;
  const int p0  = blockIdx.x * 64;
  const int b0  = p0 / N;
  const int thr = (b0 + 1) * N;
  const float bp0 = bp[0];

  // my pair (wave-local G1): pair index within block = w*16 + lr
  int p = p0 + w*16 + lr; if (p >= total) p = total - 1;
  const int  bl = (p >= thr) ? 1 : 0;
  const int  bA = b0 + bl;
  const long ib = (long)item[p] * 64;

  // ---- item mlp row -> fp8 B-fragments (registers) ----
  long a1[2];
  #pragma unroll
  for (int ks = 0; ks < 2; ks++){
    const float4* ap = (const float4*)(Wi_mlp + ib + ks*32 + lg*8);
    float4 x = ap[0], y = ap[1];
    int t0 = __builtin_amdgcn_cvt_pk_fp8_f32(x.x, x.y, 0, false);
    t0     = __builtin_amdgcn_cvt_pk_fp8_f32(x.z, x.w, t0, true);
    int t1 = __builtin_amdgcn_cvt_pk_fp8_f32(y.x, y.y, 0, false);
    t1     = __builtin_amdgcn_cvt_pk_fp8_f32(y.z, y.w, t1, true);
    i2l u; u.i.x = t0; u.i.y = t1;
    a1[ks] = u.v;
  }

  // ---- gmf partial dot (16 elems/lane, reduce over lg) ----
  float pg;
  {
    const float4* gp = (const float4*)(Wi_gmf + ib + lg*16);
    const float4* wq = (const float4*)(wup + (long)bA*64 + lg*16);
    float s = 0.f;
    #pragma unroll
    for (int j = 0; j < 4; j++){
      float4 g = gp[j], v = wq[j];
      s += g.x*v.x + g.y*v.y + g.z*v.z + g.w*v.w;
    }
    s += __shfl_xor(s, 16);
    s += __shfl_xor(s, 32);
    pg = s + cu[bA];
  }

  // ---- stage this wave's 2 Xu rows ----
  {
    int row = l >> 5;
    int col = (l & 31) * 4;
    int bb = b0 + row; if (bb >= Bsz) bb = Bsz - 1;
    *(float4*)&s_xu[w][row][col] = *(const float4*)&Xu[(long)bb*128 + col];
  }
  wave_lds_fence();

  // ---- G1 (wave-local): D[col128][pair16], K=64; +Xu, relu -> s_h1 ----
  {
    f32x4 acc[8];
    #pragma unroll
    for (int mt = 0; mt < 8; mt++) acc[mt] = (f32x4){0.f,0.f,0.f,0.f};
    #pragma unroll
    for (int ks = 0; ks < 2; ks++)
      #pragma unroll
      for (int mt = 0; mt < 8; mt++){
        long af = *(const long*)&W1iT[(mt*16 + lr)*64 + ks*32 + lg*8];
        acc[mt] = __builtin_amdgcn_mfma_f32_16x16x32_fp8_fp8(af, a1[ks], acc[mt], 0, 0, 0);
      }
    #pragma unroll
    for (int mt = 0; mt < 8; mt++){
      int colb = mt*16 + lg*4;
      float4 xv = *(const float4*)&s_xu[w][bl][colb];
      float v0 = acc[mt][0] + xv.x; v0 = v0 > 0.f ? v0 : 0.f;
      float v1 = acc[mt][1] + xv.y; v1 = v1 > 0.f ? v1 : 0.f;
      float v2 = acc[mt][2] + xv.z; v2 = v2 > 0.f ? v2 : 0.f;
      float v3 = acc[mt][3] + xv.w; v3 = v3 > 0.f ? v3 : 0.f;
      int t_ = __builtin_amdgcn_cvt_pk_fp8_f32(v0, v1, 0, false);
      t_     = __builtin_amdgcn_cvt_pk_fp8_f32(v2, v3, t_, true);
      *(int*)&s_h1[w*16 + lr][colb] = t_;
    }
  }
  __syncthreads();

  // ---- G2: wave w -> cols [w*16, w*16+16), all 64 pairs; K=128 ----
  {
    f32x4 acc2[4];
    #pragma unroll
    for (int nt = 0; nt < 4; nt++) acc2[nt] = (f32x4){0.f,0.f,0.f,0.f};
    #pragma unroll
    for (int ks = 0; ks < 4; ks++){
      long af = *(const long*)&W2T[(w*16 + lr)*128 + ks*32 + lg*8];
      #pragma unroll
      for (int nt = 0; nt < 4; nt++){
        long bf_ = *(const long*)&s_h1[nt*16 + lr][ks*32 + lg*8];
        acc2[nt] = __builtin_amdgcn_mfma_f32_16x16x32_fp8_fp8(af, bf_, acc2[nt], 0, 0, 0);
      }
    }
    int colb = w*16 + lg*4;
    float4 b2v = *(const float4*)&b2[colb];
    #pragma unroll
    for (int nt = 0; nt < 4; nt++){
      int pair = nt*16 + lr;
      float v0 = acc2[nt][0] + b2v.x; v0 = v0 > 0.f ? v0 : 0.f;
      float v1 = acc2[nt][1] + b2v.y; v1 = v1 > 0.f ? v1 : 0.f;
      float v2 = acc2[nt][2] + b2v.z; v2 = v2 > 0.f ? v2 : 0.f;
      float v3 = acc2[nt][3] + b2v.w; v3 = v3 > 0.f ? v3 : 0.f;
      int t_ = __builtin_amdgcn_cvt_pk_fp8_f32(v0, v1, 0, false);
      t_     = __builtin_amdgcn_cvt_pk_fp8_f32(v2, v3, t_, true);
      *(int*)&s_h2[pair][colb] = t_;
    }
  }
  __syncthreads();

  // ---- G3: wave w -> its 16 pairs, cols 0..31, K=64; final dot + sigmoid ----
  {
    f32x4 acc3[2];
    #pragma unroll
    for (int mt = 0; mt < 2; mt++) acc3[mt] = (f32x4){0.f,0.f,0.f,0.f};
    #pragma unroll
    for (int ks = 0; ks < 2; ks++){
      long bf_ = *(const long*)&s_h2[w*16 + lr][ks*32 + lg*8];
      #pragma unroll
      for (int mt = 0; mt < 2; mt++){
        long af = *(const long*)&W3T[(mt*16 + lr)*64 + ks*32 + lg*8];
        acc3[mt] = __builtin_amdgcn_mfma_f32_16x16x32_fp8_fp8(af, bf_, acc3[mt], 0, 0, 0);
      }
    }
    float t = 0.f;
    #pragma unroll
    for (int mt = 0; mt < 2; mt++){
      int colb = mt*16 + lg*4;
      float4 b3v = *(const float4*)&b3[colb];
      float4 wpv = *(const float4*)&Wp[64 + colb];
      float v0 = acc3[mt][0] + b3v.x; v0 = v0 > 0.f ? v0 : 0.f;
      float v1 = acc3[mt][1] + b3v.y; v1 = v1 > 0.f ? v1 : 0.f;
      float v2 = acc3[mt][2] + b3v.z; v2 = v2 > 0.f ? v2 : 0.f;
      float v3 = acc3[mt][3] + b3v.w; v3 = v3 > 0.f ? v3 : 0.f;
      t += v0*wpv.x + v1*wpv.y + v2*wpv.z + v3*wpv.w;
    }
    t += __shfl_xor(t, 16);
    t += __shfl_xor(t, 32);
    if (l < 16 && p0 + w*16 + lr < total){
      float z = t + pg + bp0;
      out[p0 + w*16 + lr] = 1.f / (1.f + __expf(-z));
    }
  }
}

extern "C" void kernel_launch(void* const* d_in, const int* in_sizes, int n_in,
                              void* d_out, int out_size, void* d_ws, size_t ws_size,
                              hipStream_t stream)
{
  const int*   user   = (const int*)  d_in[0];
  const int*   item   = (const int*)  d_in[1];
  const float* Wu_gmf = (const float*)d_in[3];
  const float* bu_gmf = (const float*)d_in[4];
  const float* Wu_mlp = (const float*)d_in[5];
  const float* bu_mlp = (const float*)d_in[6];
  const float* Wi_gmf = (const float*)d_in[7];
  const float* bi_gmf = (const float*)d_in[8];
  const float* Wi_mlp = (const float*)d_in[9];
  const float* bi_mlp = (const float*)d_in[10];
  const float* W1     = (const float*)d_in[11];
  const float* b1     = (const float*)d_in[12];
  const float* W2     = (const float*)d_in[13];
  const float* b2     = (const float*)d_in[14];
  const float* W3     = (const float*)d_in[15];
  const float* b3     = (const float*)d_in[16];
  const float* Wp     = (const float*)d_in[17];
  const float* bp     = (const float*)d_in[18];

  int B     = in_sizes[0];            // 4096
  int total = in_sizes[1];            // 409600
  int N     = total / B;              // 100

  char* wsb = (char*)d_ws;
  short*         W1uT = (short*)wsb;
  unsigned char* W1iT = (unsigned char*)(wsb + 16384);
  unsigned char* W2T  = (unsigned char*)(wsb + 24576);
  unsigned char* W3T  = (unsigned char*)(wsb + 32768);
  float*         c1   = (float*)(wsb + 34816);
  float*         Xu   = (float*)(wsb + 36864);
  float*         wup  = Xu  + (size_t)B * 128;
  float*         cuv  = wup + (size_t)B * 64;

  ncf_prep_w<<<105, 256, 0, stream>>>(W1, W2, W3, b1, bi_mlp, wsb);
  ncf_prep_u<<<B/64, 256, 0, stream>>>(user, Wu_gmf, bu_gmf, Wu_mlp, bu_mlp,
                                       bi_gmf, Wp, W1uT, c1, Xu, wup, cuv);

  int nblk = (total + 63) / 64;       // 6400
  ncf_main<<<nblk, 256, 0, stream>>>(item, Wi_mlp, Wi_gmf,
      W1iT, W2T, W3T, b2, b3, Wp, bp, Xu, wup, cuv,
      (float*)d_out, N, total, B);
}

// Round 12
// 70.216 us; speedup vs baseline: 1.7601x; 1.3093x over previous
//
#include <hip/hip_runtime.h>

// NCF fused forward, v12: v8 structure (64 pairs/block, fp8 tower, swapped GEMMs,
// 3 barriers) + VGPR trim: G1 split into 2 col-chunks, __launch_bounds__(256,6).

typedef __attribute__((ext_vector_type(8))) short bf16x8;
typedef __attribute__((ext_vector_type(4))) float f32x4;

__device__ __forceinline__ short f2bf(float x){
  unsigned u = __float_as_uint(x);
  u += 0x7fffu + ((u >> 16) & 1u);
  return (short)(u >> 16);
}
__device__ __forceinline__ unsigned char f2fp8(float x){
  return (unsigned char)(__builtin_amdgcn_cvt_pk_fp8_f32(x, 0.f, 0, false) & 0xFF);
}

// ws layout (bytes):
//   0      W1uT bf16 [128][64]  (16384)
//   16384  W1iT fp8  [128][64]  (8192)
//   24576  W2T  fp8  [64][128]  (8192)
//   32768  W3T  fp8  [32][64]   (2048)
//   34816  c1   f32  [128]
//   36864  Xu   f32  [B][128];  then wup f32 [B][64];  cu f32 [B]

__global__ __launch_bounds__(256) void ncf_prep_w(
    const float* __restrict__ W1, const float* __restrict__ W2,
    const float* __restrict__ W3, const float* __restrict__ b1,
    const float* __restrict__ bi_mlp, char* __restrict__ ws)
{
  if (blockIdx.x == 104){
    int j = threadIdx.x;
    if (j < 128){
      float acc = b1[j];
      #pragma unroll 4
      for (int k = 0; k < 64; k++)
        acc += bi_mlp[k] * W1[(64 + k)*128 + j];
      ((float*)(ws + 34816))[j] = acc;
    }
    return;
  }
  int i = blockIdx.x * 256 + threadIdx.x;
  if (i < 8192){                                 // W1uT bf16 [col][k] = W1[k][col]
    int col = i >> 6, k = i & 63;
    ((short*)ws)[i] = f2bf(W1[k*128 + col]);
  } else if (i < 16384){                         // W1iT fp8 [col][k] = W1[64+k][col]
    int t = i - 8192; int col = t >> 6, k = t & 63;
    ((unsigned char*)(ws + 16384))[t] = f2fp8(W1[(64 + k)*128 + col]);
  } else if (i < 24576){                         // W2T fp8 [col][k] = W2[k][col]
    int t = i - 16384; int col = t >> 7, k = t & 127;
    ((unsigned char*)(ws + 24576))[t] = f2fp8(W2[k*64 + col]);
  } else {                                       // W3T fp8 [col][k] = W3[k][col]
    int t = i - 24576; int col = t >> 6, k = t & 63;
    ((unsigned char*)(ws + 32768))[t] = f2fp8(W3[k*32 + col]);
  }
}

// ---- prep_u: 64 users per block, bf16 MFMA GEMM K=64 ----
__global__ __launch_bounds__(256) void ncf_prep_u(
    const int* __restrict__ user,
    const float* __restrict__ Wu_gmf, const float* __restrict__ bu_gmf,
    const float* __restrict__ Wu_mlp, const float* __restrict__ bu_mlp,
    const float* __restrict__ bi_gmf, const float* __restrict__ Wp,
    const short* __restrict__ W1uT, const float* __restrict__ c1,
    float* __restrict__ Xu, float* __restrict__ wup, float* __restrict__ cu)
{
  __shared__ __align__(16) short s_eu[64][72];
  const int tid = threadIdx.x;
  const int r = tid >> 2, q = tid & 3;
  const int b = blockIdx.x * 64 + r;
  long u = (long)user[b];
  {
    const float4* ump = (const float4*)(Wu_mlp + u*64) + q*4;
    const float4* bmp = (const float4*)(bu_mlp) + q*4;
    const float4* ugp = (const float4*)(Wu_gmf + u*64) + q*4;
    const float4* bgp = (const float4*)(bu_gmf) + q*4;
    const float4* wpp = (const float4*)(Wp) + q*4;
    const float4* bip = (const float4*)(bi_gmf) + q*4;
    float4* wdst = (float4*)(wup + (long)b*64) + q*4;
    bf16x8 ea[2];
    float cacc = 0.f;
    #pragma unroll
    for (int j = 0; j < 4; j++){
      float4 m = ump[j], mb = bmp[j];
      int h = j >> 1, s = (j & 1) * 4;
      ea[h][s+0] = f2bf(m.x + mb.x); ea[h][s+1] = f2bf(m.y + mb.y);
      ea[h][s+2] = f2bf(m.z + mb.z); ea[h][s+3] = f2bf(m.w + mb.w);
      float4 g = ugp[j], gb = bgp[j], wp = wpp[j], bi = bip[j];
      float4 wg; wg.x = (g.x+gb.x)*wp.x; wg.y = (g.y+gb.y)*wp.y;
                 wg.z = (g.z+gb.z)*wp.z; wg.w = (g.w+gb.w)*wp.w;
      wdst[j] = wg;
      cacc += wg.x*bi.x + wg.y*bi.y + wg.z*bi.z + wg.w*bi.w;
    }
    *(bf16x8*)&s_eu[r][q*16]     = ea[0];
    *(bf16x8*)&s_eu[r][q*16 + 8] = ea[1];
    cacc += __shfl_xor(cacc, 1);
    cacc += __shfl_xor(cacc, 2);
    if (q == 0) cu[b] = cacc;
  }
  __syncthreads();

  const int w = tid >> 6, l = tid & 63, lr = l & 15, lg = l >> 4;
  f32x4 acc[4][2];
  #pragma unroll
  for (int mt = 0; mt < 4; mt++)
    #pragma unroll
    for (int nt = 0; nt < 2; nt++)
      acc[mt][nt] = (f32x4){0.f, 0.f, 0.f, 0.f};
  #pragma unroll
  for (int ks = 0; ks < 2; ks++){
    bf16x8 af[4];
    #pragma unroll
    for (int mt = 0; mt < 4; mt++)
      af[mt] = *(const bf16x8*)&s_eu[mt*16 + lr][ks*32 + lg*8];
    #pragma unroll
    for (int nt = 0; nt < 2; nt++){
      bf16x8 bf_ = *(const bf16x8*)&W1uT[(w*32 + nt*16 + lr)*64 + ks*32 + lg*8];
      #pragma unroll
      for (int mt = 0; mt < 4; mt++)
        acc[mt][nt] = __builtin_amdgcn_mfma_f32_16x16x32_bf16(af[mt], bf_, acc[mt][nt], 0, 0, 0);
    }
  }
  #pragma unroll
  for (int nt = 0; nt < 2; nt++){
    int col = w*32 + nt*16 + lr;
    float cc = c1[col];
    #pragma unroll
    for (int mt = 0; mt < 4; mt++)
      #pragma unroll
      for (int rr = 0; rr < 4; rr++){
        int row = mt*16 + lg*4 + rr;
        Xu[(long)(blockIdx.x*64 + row)*128 + col] = acc[mt][nt][rr] + cc;
      }
  }
}

// ---- main: v8 structure, VGPR-trimmed ----
__global__ __launch_bounds__(256, 6) void ncf_main(
    const int* __restrict__ item,
    const float* __restrict__ Wi_mlp, const float* __restrict__ Wi_gmf,
    const unsigned char* __restrict__ W1iT, const unsigned char* __restrict__ W2T,
    const unsigned char* __restrict__ W3T,
    const float* __restrict__ b2, const float* __restrict__ b3,
    const float* __restrict__ Wp, const float* __restrict__ bp,
    const float* __restrict__ Xu, const float* __restrict__ wup,
    const float* __restrict__ cu,
    float* __restrict__ out, int N, int total, int Bsz)
{
  __shared__ __align__(16) unsigned char s_item[64][80];  // item mlp rows, fp8
  __shared__ __align__(16) unsigned char s_h1[64][136];   // h1 fp8
  __shared__ __align__(16) unsigned char s_h2[64][80];    // h2 fp8
  __shared__ __align__(16) float s_xu[2][128];
  __shared__            float s_pg[64];

  const int tid = threadIdx.x;
  const int p0  = blockIdx.x * 64;
  const int b0  = p0 / N;
  const int thr = (b0 + 1) * N;
  const int r   = tid >> 2, q = tid & 3;
  const int w   = tid >> 6, l = tid & 63;
  const int lr  = l & 15,  lg = l >> 4;
  const float bp0 = bp[0];

  // ---- store: item mlp row -> fp8 LDS; pg dot; Xu -> LDS ----
  {
    int p = p0 + r;
    int b = b0 + ((p >= thr) ? 1 : 0);
    long ib = (long)item[p] * 64;
    const float4* mp = (const float4*)(Wi_mlp + ib) + q*4;
    const float4* gp = (const float4*)(Wi_gmf + ib) + q*4;
    const float4* wq = (const float4*)(wup + (long)b*64) + q*4;
    float pg = 0.f;
    int pk[4];
    #pragma unroll
    for (int j = 0; j < 4; j++){
      float4 m = mp[j], g = gp[j], wv = wq[j];
      pg += g.x*wv.x + g.y*wv.y + g.z*wv.z + g.w*wv.w;
      int t_ = __builtin_amdgcn_cvt_pk_fp8_f32(m.x, m.y, 0, false);
      t_     = __builtin_amdgcn_cvt_pk_fp8_f32(m.z, m.w, t_, true);
      pk[j] = t_;
    }
    *(int4*)&s_item[r][q*16] = (int4){pk[0], pk[1], pk[2], pk[3]};
    pg += __shfl_xor(pg, 1);
    pg += __shfl_xor(pg, 2);
    if (q == 0) s_pg[r] = pg + cu[b];
    int i2 = tid >> 7, col = tid & 127;
    int bb = b0 + i2; if (bb >= Bsz) bb = Bsz - 1;
    s_xu[i2][col] = Xu[(long)bb*128 + col];
  }
  __syncthreads();

  // ---- G1: D[col128][pair64] fp8, K=64; +Xu, relu -> s_h1 (2 col-chunks) ----
  #pragma unroll
  for (int mt = 0; mt < 2; mt++){
    f32x4 acc[4];   // [nt] — 16 VGPR live
    #pragma unroll
    for (int nt = 0; nt < 4; nt++) acc[nt] = (f32x4){0.f, 0.f, 0.f, 0.f};
    #pragma unroll
    for (int ks = 0; ks < 2; ks++){
      long af = *(const long*)&W1iT[((w*2 + mt)*16 + lr)*64 + ks*32 + lg*8];
      #pragma unroll
      for (int nt = 0; nt < 4; nt++){
        long bf_ = *(const long*)&s_item[nt*16 + lr][ks*32 + lg*8];
        acc[nt] = __builtin_amdgcn_mfma_f32_16x16x32_fp8_fp8(af, bf_, acc[nt], 0, 0, 0);
      }
    }
    int colb = (w*2 + mt)*16 + lg*4;
    #pragma unroll
    for (int nt = 0; nt < 4; nt++){
      int pair = nt*16 + lr;
      int bl = (p0 + pair >= thr) ? 1 : 0;
      float4 xv = *(const float4*)&s_xu[bl][colb];
      float v0 = acc[nt][0] + xv.x; v0 = v0 > 0.f ? v0 : 0.f;
      float v1 = acc[nt][1] + xv.y; v1 = v1 > 0.f ? v1 : 0.f;
      float v2 = acc[nt][2] + xv.z; v2 = v2 > 0.f ? v2 : 0.f;
      float v3 = acc[nt][3] + xv.w; v3 = v3 > 0.f ? v3 : 0.f;
      int t_ = __builtin_amdgcn_cvt_pk_fp8_f32(v0, v1, 0, false);
      t_     = __builtin_amdgcn_cvt_pk_fp8_f32(v2, v3, t_, true);
      *(int*)&s_h1[pair][colb] = t_;
    }
  }
  __syncthreads();

  // ---- G2: D[col64][pair64] fp8, K=128; +b2, relu -> s_h2 ----
  {
    f32x4 acc[4];   // [nt]
    #pragma unroll
    for (int nt = 0; nt < 4; nt++) acc[nt] = (f32x4){0.f, 0.f, 0.f, 0.f};
    #pragma unroll
    for (int ks = 0; ks < 4; ks++){
      long af = *(const long*)&W2T[(w*16 + lr)*128 + ks*32 + lg*8];
      #pragma unroll
      for (int nt = 0; nt < 4; nt++){
        long bf_ = *(const long*)&s_h1[nt*16 + lr][ks*32 + lg*8];
        acc[nt] = __builtin_amdgcn_mfma_f32_16x16x32_fp8_fp8(af, bf_, acc[nt], 0, 0, 0);
      }
    }
    int colb = w*16 + lg*4;
    float4 b2v = *(const float4*)&b2[colb];
    #pragma unroll
    for (int nt = 0; nt < 4; nt++){
      int pair = nt*16 + lr;
      float v0 = acc[nt][0] + b2v.x; v0 = v0 > 0.f ? v0 : 0.f;
      float v1 = acc[nt][1] + b2v.y; v1 = v1 > 0.f ? v1 : 0.f;
      float v2 = acc[nt][2] + b2v.z; v2 = v2 > 0.f ? v2 : 0.f;
      float v3 = acc[nt][3] + b2v.w; v3 = v3 > 0.f ? v3 : 0.f;
      int t_ = __builtin_amdgcn_cvt_pk_fp8_f32(v0, v1, 0, false);
      t_     = __builtin_amdgcn_cvt_pk_fp8_f32(v2, v3, t_, true);
      *(int*)&s_h2[pair][colb] = t_;
    }
  }
  __syncthreads();

  // ---- G3: D[col32][pair16/wave] fp8, K=64; final dot + sigmoid ----
  {
    f32x4 acc[2];   // [mt]
    #pragma unroll
    for (int mt = 0; mt < 2; mt++) acc[mt] = (f32x4){0.f, 0.f, 0.f, 0.f};
    #pragma unroll
    for (int ks = 0; ks < 2; ks++){
      long bf_ = *(const long*)&s_h2[w*16 + lr][ks*32 + lg*8];
      #pragma unroll
      for (int mt = 0; mt < 2; mt++){
        long af = *(const long*)&W3T[(mt*16 + lr)*64 + ks*32 + lg*8];
        acc[mt] = __builtin_amdgcn_mfma_f32_16x16x32_fp8_fp8(af, bf_, acc[mt], 0, 0, 0);
      }
    }
    float t = 0.f;
    #pragma unroll
    for (int mt = 0; mt < 2; mt++){
      int colb = mt*16 + lg*4;
      float4 b3v = *(const float4*)&b3[colb];
      float4 wpv = *(const float4*)&Wp[64 + colb];
      float v0 = acc[mt][0] + b3v.x; v0 = v0 > 0.f ? v0 : 0.f;
      float v1 = acc[mt][1] + b3v.y; v1 = v1 > 0.f ? v1 : 0.f;
      float v2 = acc[mt][2] + b3v.z; v2 = v2 > 0.f ? v2 : 0.f;
      float v3 = acc[mt][3] + b3v.w; v3 = v3 > 0.f ? v3 : 0.f;
      t += v0*wpv.x + v1*wpv.y + v2*wpv.z + v3*wpv.w;
    }
    t += __shfl_xor(t, 16);
    t += __shfl_xor(t, 32);
    if (l < 16){
      int pair = w*16 + l;
      int p = p0 + pair;
      if (p < total){
        float z = t + s_pg[pair] + bp0;
        out[p] = 1.f / (1.f + __expf(-z));
      }
    }
  }
}

extern "C" void kernel_launch(void* const* d_in, const int* in_sizes, int n_in,
                              void* d_out, int out_size, void* d_ws, size_t ws_size,
                              hipStream_t stream)
{
  const int*   user   = (const int*)  d_in[0];
  const int*   item   = (const int*)  d_in[1];
  const float* Wu_gmf = (const float*)d_in[3];
  const float* bu_gmf = (const float*)d_in[4];
  const float* Wu_mlp = (const float*)d_in[5];
  const float* bu_mlp = (const float*)d_in[6];
  const float* Wi_gmf = (const float*)d_in[7];
  const float* bi_gmf = (const float*)d_in[8];
  const float* Wi_mlp = (const float*)d_in[9];
  const float* bi_mlp = (const float*)d_in[10];
  const float* W1     = (const float*)d_in[11];
  const float* b1     = (const float*)d_in[12];
  const float* W2     = (const float*)d_in[13];
  const float* b2     = (const float*)d_in[14];
  const float* W3     = (const float*)d_in[15];
  const float* b3     = (const float*)d_in[16];
  const float* Wp     = (const float*)d_in[17];
  const float* bp     = (const float*)d_in[18];

  int B     = in_sizes[0];            // 4096
  int total = in_sizes[1];            // 409600
  int N     = total / B;              // 100

  char* wsb = (char*)d_ws;
  short*         W1uT = (short*)wsb;
  unsigned char* W1iT = (unsigned char*)(wsb + 16384);
  unsigned char* W2T  = (unsigned char*)(wsb + 24576);
  unsigned char* W3T  = (unsigned char*)(wsb + 32768);
  float*         c1   = (float*)(wsb + 34816);
  float*         Xu   = (float*)(wsb + 36864);
  float*         wup  = Xu  + (size_t)B * 128;
  float*         cuv  = wup + (size_t)B * 64;

  ncf_prep_w<<<105, 256, 0, stream>>>(W1, W2, W3, b1, bi_mlp, wsb);
  ncf_prep_u<<<B/64, 256, 0, stream>>>(user, Wu_gmf, bu_gmf, Wu_mlp, bu_mlp,
                                       bi_gmf, Wp, W1uT, c1, Xu, wup, cuv);

  int nblk = (total + 63) / 64;       // 6400
  ncf_main<<<nblk, 256, 0, stream>>>(item, Wi_mlp, Wi_gmf,
      W1iT, W2T, W3T, b2, b3, Wp, bp, Xu, wup, cuv,
      (float*)d_out, N, total, B);
}